// Round 3
// baseline (632.554 us; speedup 1.0000x reference)
//
#include <hip/hip_runtime.h>
#include <cstddef>

// ============================================================================
// VLSTM via bf16 MFMA, R3: occupancy-first.
//  - 512 blocks x 512 threads (8 waves), 64 nodes/block, persistent T=20.
//  - Weights STREAMED from global (L2-resident) each kb instead of living in
//    96 VGPRs -> peak VGPR ~120 -> __launch_bounds__(512,4) -> 2 blocks/CU,
//    so one block's MFMA overlaps the other's activation VALU.
//  - A = [emb(64)|h(128)] bf16 in LDS, MFMA A-fragment order (unchanged, R2).
//  - Out-projection = MFMA with zero-padded W_out B-fragment on waves 0..3.
//  - 2 barriers/step: B2 (GEMM reads done), B3 (h-write + emb(t+1) done).
//    Mask is double-buffered so the t+1 stage never races step-t readers.
// ============================================================================

typedef __attribute__((ext_vector_type(8))) short  s16x8;   // 8 x bf16
typedef __attribute__((ext_vector_type(4))) float  f32x4;

namespace {
constexpr int T_STEPS = 20;
constexpr int NN      = 32768;
constexpr int D_EMB   = 64;
constexpr int D_H     = 128;
constexpr int D_OUT   = 5;
constexpr int G4      = 512;
constexpr int MT      = 64;
constexpr int BLOCK   = 512;
constexpr int GRID    = NN / MT;
constexpr int WP_ELEMS   = 8 * 4 * 6 * 64 * 8;   // gate-weight fragments
constexpr int WOUT_ELEMS = 4 * 64 * 8;           // W_out fragments (padded)
constexpr size_t OFF_H = (size_t)T_STEPS * NN * D_OUT;
constexpr size_t OFF_C = OFF_H + (size_t)NN * D_H;
}

__device__ __forceinline__ unsigned short f2bf(float x) {
    unsigned u = __float_as_uint(x);
    u = (u + 0x7FFFu + ((u >> 16) & 1u)) >> 16;     // RNE
    return (unsigned short)u;
}
__device__ __forceinline__ float bf2f(unsigned short h) {
    return __uint_as_float(((unsigned)h) << 16);
}
__device__ __forceinline__ float sigf(float x) {
    return __builtin_amdgcn_rcpf(1.0f + __expf(-x));     // x=+-inf safe
}
__device__ __forceinline__ float tanhf_fast(float x) {
    // 1 - 2/(1+e^{2x}); exp overflow -> rcp(inf)=0 -> 1; underflow -> -1.
    return fmaf(-2.0f, __builtin_amdgcn_rcpf(1.0f + __expf(2.0f * x)), 1.0f);
}

// ----------------------------------------------------------------------------
// Pre-pack:
//  Wp[w][g][kb][L][j]  = Wcat[k = kb*32+(L>>4)*8+j][col = g*128+w*16+(L&15)]
//  WoutF[kb2][L][j]    = (L&15)<5 ? W_out[k = kb2*32+(L>>4)*8+j][L&15] : 0
//  b_sum[col]          = b_ih[col] + b_hh[col]
// ----------------------------------------------------------------------------
__global__ void prepack_kernel(const float* __restrict__ W_ih,
                               const float* __restrict__ b_ih,
                               const float* __restrict__ W_hh,
                               const float* __restrict__ b_hh,
                               const float* __restrict__ W_out,
                               unsigned short* __restrict__ Wp,
                               unsigned short* __restrict__ WoutF,
                               float* __restrict__ b_sum) {
    int idx = blockIdx.x * blockDim.x + threadIdx.x;
    if (idx < WP_ELEMS) {
        int j    = idx & 7;
        int L    = (idx >> 3) & 63;
        int rest = idx >> 9;
        int kb   = rest % 6;
        int gw   = rest / 6;
        int g    = gw & 3, w = gw >> 2;
        int k    = kb * 32 + (L >> 4) * 8 + j;
        int col  = g * D_H + w * 16 + (L & 15);
        float v  = (k < D_EMB) ? W_ih[k * G4 + col] : W_hh[(k - D_EMB) * G4 + col];
        Wp[idx] = f2bf(v);
    } else if (idx < WP_ELEMS + WOUT_ELEMS) {
        int i2 = idx - WP_ELEMS;
        int j = i2 & 7, L = (i2 >> 3) & 63, kb2 = i2 >> 9;
        int k = kb2 * 32 + (L >> 4) * 8 + j;
        int n = L & 15;
        WoutF[i2] = (n < D_OUT) ? f2bf(W_out[k * D_OUT + n]) : (unsigned short)0;
    }
    if (idx < G4) b_sum[idx] = b_ih[idx] + b_hh[idx];
}

// ----------------------------------------------------------------------------
__global__ __launch_bounds__(BLOCK, 4) void vlstm_kernel(
    const float* __restrict__ nodes,   // [T][N][2]
    const int*   __restrict__ mask,    // [T][N]
    const float* __restrict__ h0,      // [N][128]
    const float* __restrict__ c0,      // [N][128]
    const float* __restrict__ W_embed, // [2][64]
    const float* __restrict__ b_embed, // [64]
    const float* __restrict__ b_out,   // [5]
    const unsigned short* __restrict__ Wp,
    const unsigned short* __restrict__ WoutF,
    const float* __restrict__ b_sum,
    float* __restrict__ out)
{
    __shared__ __align__(16) unsigned short A[24 * 64 * 8];   // 24 KB
    __shared__ float We_s[2 * D_EMB];
    __shared__ float be_s[D_EMB];
    __shared__ int   msk_s[2][MT];

    const int tid  = threadIdx.x;
    const int wave = tid >> 6;
    const int L    = tid & 63;
    const int quad = L >> 4;
    const int l15  = L & 15;
    const int n_base = blockIdx.x * MT;

    float bias[4];
    #pragma unroll
    for (int g = 0; g < 4; g++) bias[g] = b_sum[g * D_H + wave * 16 + l15];
    const float bo = (l15 < D_OUT) ? b_out[l15] : 0.0f;

    // ---- one-time LDS staging ----
    for (int i = tid; i < 3 * D_EMB; i += BLOCK) {
        if (i < 2 * D_EMB) We_s[i] = W_embed[i];
        else               be_s[i - 2 * D_EMB] = b_embed[i - 2 * D_EMB];
    }
    for (int i = tid; i < MT * D_H; i += BLOCK) {   // h0 -> A rows 64..191
        int node = i >> 7, u = i & 127;
        int k = D_EMB + u;
        int idx = (((node >> 4) * 6 + (k >> 5)) * 64 + ((k >> 3) & 3) * 16 + (node & 15)) * 8 + (k & 7);
        A[idx] = f2bf(h0[(size_t)(n_base + node) * D_H + u]);
    }
    const int u_lane = wave * 16 + l15;
    float c[4][4];
    #pragma unroll
    for (int rt = 0; rt < 4; rt++)
        #pragma unroll
        for (int r = 0; r < 4; r++) {
            int m = rt * 16 + quad * 4 + r;
            c[rt][r] = c0[(size_t)(n_base + m) * D_H + u_lane];
        }
    __syncthreads();   // staging (We_s/be_s/A-h) visible

    const int node_e = tid >> 3;
    const int eb     = tid & 7;
    const unsigned short* wbase = Wp + (size_t)wave * (4 * 6 * 64 * 8);

    // ---- emb(0) + mask(0) ----
    {
        const float2* xp = (const float2*)(nodes + ((size_t)0 * NN + n_base + node_e) * 2);
        float2 x = *xp;
        s16x8 ev;
        #pragma unroll
        for (int j = 0; j < 8; j++) {
            int e = eb * 8 + j;
            float v = fmaf(x.x, We_s[e], fmaf(x.y, We_s[D_EMB + e], be_s[e]));
            ev[j] = (short)f2bf(fmaxf(v, 0.0f));
        }
        int idx = (((node_e >> 4) * 6 + (eb >> 2)) * 64 + (eb & 3) * 16 + (node_e & 15)) * 8;
        *(s16x8*)(A + idx) = ev;
        if (tid < MT) msk_s[0][tid] = mask[(size_t)0 * NN + n_base + tid];
    }
    __syncthreads();   // B1(0): A + mask ready

    for (int t = 0; t < T_STEPS; t++) {
        // ---- gate GEMM: weights streamed from global (L2-hot) ----
        f32x4 acc[4][4];
        #pragma unroll
        for (int rt = 0; rt < 4; rt++)
            #pragma unroll
            for (int g = 0; g < 4; g++)
                acc[rt][g] = (f32x4){bias[g], bias[g], bias[g], bias[g]};

        s16x8 bc[4], bn[4];
        #pragma unroll
        for (int g = 0; g < 4; g++)
            bc[g] = *(const s16x8*)(wbase + ((g * 6 + 0) * 64 + L) * 8);
        #pragma unroll
        for (int kb = 0; kb < 6; kb++) {
            if (kb < 5) {
                #pragma unroll
                for (int g = 0; g < 4; g++)
                    bn[g] = *(const s16x8*)(wbase + ((g * 6 + kb + 1) * 64 + L) * 8);
            }
            #pragma unroll
            for (int rt = 0; rt < 4; rt++) {
                s16x8 af = *(const s16x8*)(A + ((rt * 6 + kb) * 64 + L) * 8);
                #pragma unroll
                for (int g = 0; g < 4; g++)
                    acc[rt][g] = __builtin_amdgcn_mfma_f32_16x16x32_bf16(
                        af, bc[g], acc[rt][g], 0, 0, 0);
            }
            #pragma unroll
            for (int g = 0; g < 4; g++) bc[g] = bn[g];
        }

        // ---- activations: lane-local ----
        unsigned mbits = 0;
        unsigned short hbf[4][4];
        #pragma unroll
        for (int rt = 0; rt < 4; rt++)
            #pragma unroll
            for (int r = 0; r < 4; r++) {
                int m = rt * 16 + quad * 4 + r;
                int mval = msk_s[t & 1][m];
                float gi = sigf(acc[rt][0][r]);
                float gf = sigf(acc[rt][1][r]);
                float gg = tanhf_fast(acc[rt][2][r]);
                float go = sigf(acc[rt][3][r]);
                float cn = fmaf(gf, c[rt][r], gi * gg);
                float hv = go * tanhf_fast(cn);
                if (mval) { c[rt][r] = cn; mbits |= 1u << (rt * 4 + r); }
                hbf[rt][r] = f2bf(hv);
            }
        __syncthreads();   // B2: all GEMM reads of A done

        // ---- h-write (masked) + emb(t+1) + mask(t+1) ----
        {
            int kb_u = 2 + (u_lane >> 5);
            int fl   = ((u_lane >> 3) & 3) * 16 + quad * 4;
            int j_u  = u_lane & 7;
            #pragma unroll
            for (int rt = 0; rt < 4; rt++)
                #pragma unroll
                for (int r = 0; r < 4; r++)
                    if ((mbits >> (rt * 4 + r)) & 1u)
                        A[((rt * 6 + kb_u) * 64 + fl + r) * 8 + j_u] = hbf[rt][r];
        }
        if (t + 1 < T_STEPS) {
            const float2* xp = (const float2*)(nodes + ((size_t)(t + 1) * NN + n_base + node_e) * 2);
            float2 x = *xp;
            s16x8 ev;
            #pragma unroll
            for (int j = 0; j < 8; j++) {
                int e = eb * 8 + j;
                float v = fmaf(x.x, We_s[e], fmaf(x.y, We_s[D_EMB + e], be_s[e]));
                ev[j] = (short)f2bf(fmaxf(v, 0.0f));
            }
            int idx = (((node_e >> 4) * 6 + (eb >> 2)) * 64 + (eb & 3) * 16 + (node_e & 15)) * 8;
            *(s16x8*)(A + idx) = ev;
            if (tid < MT) msk_s[(t + 1) & 1][tid] = mask[(size_t)(t + 1) * NN + n_base + tid];
        }
        __syncthreads();   // B3: new h (+ next emb/mask) visible

        // ---- out(t) = mask ? h_new @ W_out + b_out : 0  (MFMA, waves 0..3) --
        // Safe without a trailing barrier: the next writer of A h-rows is the
        // h-write after B2(t+1), and waves 0..3 only reach B2(t+1) after
        // finishing this phase.
        if (wave < 4) {
            const int rt = wave;
            f32x4 ao = (f32x4){0.0f, 0.0f, 0.0f, 0.0f};
            #pragma unroll
            for (int kb2 = 0; kb2 < 4; kb2++) {
                s16x8 wf = *(const s16x8*)(WoutF + ((kb2 * 64) + L) * 8);
                s16x8 af = *(const s16x8*)(A + ((rt * 6 + 2 + kb2) * 64 + L) * 8);
                ao = __builtin_amdgcn_mfma_f32_16x16x32_bf16(af, wf, ao, 0, 0, 0);
            }
            if (l15 < D_OUT) {
                #pragma unroll
                for (int r = 0; r < 4; r++) {
                    int node = rt * 16 + quad * 4 + r;
                    int mv = msk_s[t & 1][node];
                    float v = mv ? (ao[r] + bo) : 0.0f;
                    out[((size_t)t * NN + n_base + node) * D_OUT + l15] = v;
                }
            }
        }
    }

    // ---- epilogue: h_fin from A (bf16), c_fin exact fp32 from regs ----
    for (int i = tid; i < MT * D_H; i += BLOCK) {
        int node = i >> 7, u = i & 127;
        int k = D_EMB + u;
        int idx = (((node >> 4) * 6 + (k >> 5)) * 64 + ((k >> 3) & 3) * 16 + (node & 15)) * 8 + (k & 7);
        out[OFF_H + (size_t)(n_base + node) * D_H + u] = bf2f(A[idx]);
    }
    #pragma unroll
    for (int rt = 0; rt < 4; rt++)
        #pragma unroll
        for (int r = 0; r < 4; r++) {
            int m = rt * 16 + quad * 4 + r;
            out[OFF_C + (size_t)(n_base + m) * D_H + u_lane] = c[rt][r];
        }
}

extern "C" void kernel_launch(void* const* d_in, const int* in_sizes, int n_in,
                              void* d_out, int out_size, void* d_ws, size_t ws_size,
                              hipStream_t stream) {
    const float* nodes   = (const float*)d_in[0];
    const int*   mask    = (const int*)  d_in[1];
    const float* h0      = (const float*)d_in[2];
    const float* c0      = (const float*)d_in[3];
    const float* W_embed = (const float*)d_in[4];
    const float* b_embed = (const float*)d_in[5];
    const float* W_ih    = (const float*)d_in[6];
    const float* b_ih    = (const float*)d_in[7];
    const float* W_hh    = (const float*)d_in[8];
    const float* b_hh    = (const float*)d_in[9];
    const float* W_out   = (const float*)d_in[10];
    const float* b_out   = (const float*)d_in[11];
    float* out = (float*)d_out;

    unsigned short* Wp    = (unsigned short*)d_ws;
    unsigned short* WoutF = Wp + WP_ELEMS;
    float*          b_sum = (float*)(WoutF + WOUT_ELEMS);

    prepack_kernel<<<(WP_ELEMS + WOUT_ELEMS + 255) / 256, 256, 0, stream>>>(
        W_ih, b_ih, W_hh, b_hh, W_out, Wp, WoutF, b_sum);

    vlstm_kernel<<<GRID, BLOCK, 0, stream>>>(
        nodes, mask, h0, c0, W_embed, b_embed, b_out, Wp, WoutF, b_sum, out);
}

// Round 4
// 331.319 us; speedup vs baseline: 1.9092x; 1.9092x over previous
//
#include <hip/hip_runtime.h>
#include <cstddef>

// ============================================================================
// VLSTM via bf16 MFMA, R4: register-resident weights (R2) + rcpf activations,
// MFMA out-projection, 2 barriers/step (R3) + LDS-staged coalesced out-stores.
//  - 512 blocks x 512 threads (8 waves), 64 nodes/block, persistent T=20.
//  - Weights: each wave's 24 B-fragments (4 gates x 6 kb, 96 VGPR) loaded ONCE
//    from the pre-packed d_ws image. R3 proved streaming them per-step costs
//    1.7 GB of HBM (L2 does NOT retain them across 512 skewed blocks).
//  - A = [emb(64)|h(128)] bf16 in LDS, MFMA A-fragment order.
//  - out stores: out-proj MFMA writes masked results to a 1.3 KB LDS staging
//    tile; stored one step later as a single coalesced 1280 B burst by 320
//    linear threads (fixes R3's 330 MB partial-line RMW write amplification).
// ============================================================================

typedef __attribute__((ext_vector_type(8))) short  s16x8;   // 8 x bf16
typedef __attribute__((ext_vector_type(4))) float  f32x4;

namespace {
constexpr int T_STEPS = 20;
constexpr int NN      = 32768;
constexpr int D_EMB   = 64;
constexpr int D_H     = 128;
constexpr int D_OUT   = 5;
constexpr int G4      = 512;
constexpr int MT      = 64;
constexpr int BLOCK   = 512;
constexpr int GRID    = NN / MT;
constexpr int WP_ELEMS   = 8 * 4 * 6 * 64 * 8;
constexpr int WOUT_ELEMS = 4 * 64 * 8;
constexpr size_t OFF_H = (size_t)T_STEPS * NN * D_OUT;
constexpr size_t OFF_C = OFF_H + (size_t)NN * D_H;
}

__device__ __forceinline__ unsigned short f2bf(float x) {
    unsigned u = __float_as_uint(x);
    u = (u + 0x7FFFu + ((u >> 16) & 1u)) >> 16;     // RNE
    return (unsigned short)u;
}
__device__ __forceinline__ float bf2f(unsigned short h) {
    return __uint_as_float(((unsigned)h) << 16);
}
__device__ __forceinline__ float sigf(float x) {
    return __builtin_amdgcn_rcpf(1.0f + __expf(-x));
}
__device__ __forceinline__ float tanhf_fast(float x) {
    return fmaf(-2.0f, __builtin_amdgcn_rcpf(1.0f + __expf(2.0f * x)), 1.0f);
}

// ----------------------------------------------------------------------------
__global__ void prepack_kernel(const float* __restrict__ W_ih,
                               const float* __restrict__ b_ih,
                               const float* __restrict__ W_hh,
                               const float* __restrict__ b_hh,
                               const float* __restrict__ W_out,
                               unsigned short* __restrict__ Wp,
                               unsigned short* __restrict__ WoutF,
                               float* __restrict__ b_sum) {
    int idx = blockIdx.x * blockDim.x + threadIdx.x;
    if (idx < WP_ELEMS) {
        int j    = idx & 7;
        int L    = (idx >> 3) & 63;
        int rest = idx >> 9;
        int kb   = rest % 6;
        int gw   = rest / 6;
        int g    = gw & 3, w = gw >> 2;
        int k    = kb * 32 + (L >> 4) * 8 + j;
        int col  = g * D_H + w * 16 + (L & 15);
        float v  = (k < D_EMB) ? W_ih[k * G4 + col] : W_hh[(k - D_EMB) * G4 + col];
        Wp[idx] = f2bf(v);
    } else if (idx < WP_ELEMS + WOUT_ELEMS) {
        int i2 = idx - WP_ELEMS;
        int j = i2 & 7, L = (i2 >> 3) & 63, kb2 = i2 >> 9;
        int k = kb2 * 32 + (L >> 4) * 8 + j;
        int n = L & 15;
        WoutF[i2] = (n < D_OUT) ? f2bf(W_out[k * D_OUT + n]) : (unsigned short)0;
    }
    if (idx < G4) b_sum[idx] = b_ih[idx] + b_hh[idx];
}

// ----------------------------------------------------------------------------
__global__ __launch_bounds__(BLOCK, 2) void vlstm_kernel(
    const float* __restrict__ nodes,   // [T][N][2]
    const int*   __restrict__ mask,    // [T][N]
    const float* __restrict__ h0,      // [N][128]
    const float* __restrict__ c0,      // [N][128]
    const float* __restrict__ W_embed, // [2][64]
    const float* __restrict__ b_embed, // [64]
    const float* __restrict__ b_out,   // [5]
    const unsigned short* __restrict__ Wp,
    const unsigned short* __restrict__ WoutF,
    const float* __restrict__ b_sum,
    float* __restrict__ out)
{
    __shared__ __align__(16) unsigned short A[24 * 64 * 8];   // 24 KB
    __shared__ __align__(16) float st_out[MT * D_OUT];        // 1.3 KB staging
    __shared__ float We_s[2 * D_EMB];
    __shared__ float be_s[D_EMB];
    __shared__ int   msk_s[2][MT];

    const int tid  = threadIdx.x;
    const int wave = tid >> 6;
    const int L    = tid & 63;
    const int quad = L >> 4;
    const int l15  = L & 15;
    const int n_base = blockIdx.x * MT;

    // ---- weights -> registers, once ----
    const unsigned short* wbase = Wp + (size_t)wave * (4 * 6 * 64 * 8);
    s16x8 Bf[4][6];
    #pragma unroll
    for (int g = 0; g < 4; g++)
        #pragma unroll
        for (int kb = 0; kb < 6; kb++)
            Bf[g][kb] = *(const s16x8*)(wbase + ((g * 6 + kb) * 64 + L) * 8);
    s16x8 WoF[4];
    #pragma unroll
    for (int kb2 = 0; kb2 < 4; kb2++)
        WoF[kb2] = *(const s16x8*)(WoutF + ((kb2 * 64) + L) * 8);

    float bias[4];
    #pragma unroll
    for (int g = 0; g < 4; g++) bias[g] = b_sum[g * D_H + wave * 16 + l15];
    const float bo = (l15 < D_OUT) ? b_out[l15] : 0.0f;

    // ---- one-time LDS staging ----
    for (int i = tid; i < 3 * D_EMB; i += BLOCK) {
        if (i < 2 * D_EMB) We_s[i] = W_embed[i];
        else               be_s[i - 2 * D_EMB] = b_embed[i - 2 * D_EMB];
    }
    for (int i = tid; i < MT * D_H; i += BLOCK) {   // h0 -> A rows 64..191
        int node = i >> 7, u = i & 127;
        int k = D_EMB + u;
        int idx = (((node >> 4) * 6 + (k >> 5)) * 64 + ((k >> 3) & 3) * 16 + (node & 15)) * 8 + (k & 7);
        A[idx] = f2bf(h0[(size_t)(n_base + node) * D_H + u]);
    }
    const int u_lane = wave * 16 + l15;
    float c[4][4];
    #pragma unroll
    for (int rt = 0; rt < 4; rt++)
        #pragma unroll
        for (int r = 0; r < 4; r++) {
            int m = rt * 16 + quad * 4 + r;
            c[rt][r] = c0[(size_t)(n_base + m) * D_H + u_lane];
        }
    __syncthreads();

    const int node_e = tid >> 3;
    const int eb     = tid & 7;

    // ---- emb(0) + mask(0) ----
    {
        const float2* xp = (const float2*)(nodes + ((size_t)0 * NN + n_base + node_e) * 2);
        float2 x = *xp;
        s16x8 ev;
        #pragma unroll
        for (int j = 0; j < 8; j++) {
            int e = eb * 8 + j;
            float v = fmaf(x.x, We_s[e], fmaf(x.y, We_s[D_EMB + e], be_s[e]));
            ev[j] = (short)f2bf(fmaxf(v, 0.0f));
        }
        int idx = (((node_e >> 4) * 6 + (eb >> 2)) * 64 + (eb & 3) * 16 + (node_e & 15)) * 8;
        *(s16x8*)(A + idx) = ev;
        if (tid < MT) msk_s[0][tid] = mask[(size_t)0 * NN + n_base + tid];
    }
    __syncthreads();   // B1(0)

    for (int t = 0; t < T_STEPS; t++) {
        // ---- gate GEMM: register weights, 24 ds_read_b128 + 96 MFMA/wave ----
        f32x4 acc[4][4];
        #pragma unroll
        for (int rt = 0; rt < 4; rt++)
            #pragma unroll
            for (int g = 0; g < 4; g++)
                acc[rt][g] = (f32x4){bias[g], bias[g], bias[g], bias[g]};
        #pragma unroll
        for (int kb = 0; kb < 6; kb++) {
            #pragma unroll
            for (int rt = 0; rt < 4; rt++) {
                s16x8 af = *(const s16x8*)(A + ((rt * 6 + kb) * 64 + L) * 8);
                #pragma unroll
                for (int g = 0; g < 4; g++)
                    acc[rt][g] = __builtin_amdgcn_mfma_f32_16x16x32_bf16(
                        af, Bf[g][kb], acc[rt][g], 0, 0, 0);
            }
        }

        // ---- activations (lane-local) ----
        unsigned mbits = 0;
        unsigned short hbf[4][4];
        #pragma unroll
        for (int rt = 0; rt < 4; rt++)
            #pragma unroll
            for (int r = 0; r < 4; r++) {
                int m = rt * 16 + quad * 4 + r;
                int mval = msk_s[t & 1][m];
                float gi = sigf(acc[rt][0][r]);
                float gf = sigf(acc[rt][1][r]);
                float gg = tanhf_fast(acc[rt][2][r]);
                float go = sigf(acc[rt][3][r]);
                float cn = fmaf(gf, c[rt][r], gi * gg);
                float hv = go * tanhf_fast(cn);
                if (mval) { c[rt][r] = cn; mbits |= 1u << (rt * 4 + r); }
                hbf[rt][r] = f2bf(hv);
            }
        __syncthreads();   // B2(t): all GEMM reads of A done; st_out(t-1) ready

        // ---- coalesced store of out(t-1) from staging ----
        if (t > 0 && tid < MT * D_OUT)
            out[((size_t)(t - 1) * NN + n_base) * D_OUT + tid] = st_out[tid];

        // ---- h-write (masked) + emb(t+1) + mask(t+1) ----
        {
            int kb_u = 2 + (u_lane >> 5);
            int fl   = ((u_lane >> 3) & 3) * 16 + quad * 4;
            int j_u  = u_lane & 7;
            #pragma unroll
            for (int rt = 0; rt < 4; rt++)
                #pragma unroll
                for (int r = 0; r < 4; r++)
                    if ((mbits >> (rt * 4 + r)) & 1u)
                        A[((rt * 6 + kb_u) * 64 + fl + r) * 8 + j_u] = hbf[rt][r];
        }
        if (t + 1 < T_STEPS) {
            const float2* xp = (const float2*)(nodes + ((size_t)(t + 1) * NN + n_base + node_e) * 2);
            float2 x = *xp;
            s16x8 ev;
            #pragma unroll
            for (int j = 0; j < 8; j++) {
                int e = eb * 8 + j;
                float v = fmaf(x.x, We_s[e], fmaf(x.y, We_s[D_EMB + e], be_s[e]));
                ev[j] = (short)f2bf(fmaxf(v, 0.0f));
            }
            int idx = (((node_e >> 4) * 6 + (eb >> 2)) * 64 + (eb & 3) * 16 + (node_e & 15)) * 8;
            *(s16x8*)(A + idx) = ev;
            if (tid < MT) msk_s[(t + 1) & 1][tid] = mask[(size_t)(t + 1) * NN + n_base + tid];
        }
        __syncthreads();   // B3(t): new h + next emb/mask visible

        // ---- out-proj(t): MFMA on waves 0..3, masked result -> LDS staging --
        // st_out(t) writes land before these waves reach B2(t+1); readers of
        // st_out(t) run after B2(t+1). A h-rows stable until h-write(t+1),
        // which is also post-B2(t+1).
        if (wave < 4) {
            const int rt = wave;
            f32x4 ao = (f32x4){0.0f, 0.0f, 0.0f, 0.0f};
            #pragma unroll
            for (int kb2 = 0; kb2 < 4; kb2++) {
                s16x8 af = *(const s16x8*)(A + ((rt * 6 + 2 + kb2) * 64 + L) * 8);
                ao = __builtin_amdgcn_mfma_f32_16x16x32_bf16(af, WoF[kb2], ao, 0, 0, 0);
            }
            if (l15 < D_OUT) {
                #pragma unroll
                for (int r = 0; r < 4; r++) {
                    int node = rt * 16 + quad * 4 + r;
                    int mv = msk_s[t & 1][node];
                    st_out[node * D_OUT + l15] = mv ? (ao[r] + bo) : 0.0f;
                }
            }
        }
    }

    __syncthreads();   // st_out(19) visible
    if (tid < MT * D_OUT)
        out[((size_t)(T_STEPS - 1) * NN + n_base) * D_OUT + tid] = st_out[tid];

    // ---- epilogue: h_fin from A (bf16), c_fin exact fp32 from regs ----
    for (int i = tid; i < MT * D_H; i += BLOCK) {
        int node = i >> 7, u = i & 127;
        int k = D_EMB + u;
        int idx = (((node >> 4) * 6 + (k >> 5)) * 64 + ((k >> 3) & 3) * 16 + (node & 15)) * 8 + (k & 7);
        out[OFF_H + (size_t)(n_base + node) * D_H + u] = bf2f(A[idx]);
    }
    #pragma unroll
    for (int rt = 0; rt < 4; rt++)
        #pragma unroll
        for (int r = 0; r < 4; r++) {
            int m = rt * 16 + quad * 4 + r;
            out[OFF_C + (size_t)(n_base + m) * D_H + u_lane] = c[rt][r];
        }
}

extern "C" void kernel_launch(void* const* d_in, const int* in_sizes, int n_in,
                              void* d_out, int out_size, void* d_ws, size_t ws_size,
                              hipStream_t stream) {
    const float* nodes   = (const float*)d_in[0];
    const int*   mask    = (const int*)  d_in[1];
    const float* h0      = (const float*)d_in[2];
    const float* c0      = (const float*)d_in[3];
    const float* W_embed = (const float*)d_in[4];
    const float* b_embed = (const float*)d_in[5];
    const float* W_ih    = (const float*)d_in[6];
    const float* b_ih    = (const float*)d_in[7];
    const float* W_hh    = (const float*)d_in[8];
    const float* b_hh    = (const float*)d_in[9];
    const float* W_out   = (const float*)d_in[10];
    const float* b_out   = (const float*)d_in[11];
    float* out = (float*)d_out;

    unsigned short* Wp    = (unsigned short*)d_ws;
    unsigned short* WoutF = Wp + WP_ELEMS;
    float*          b_sum = (float*)(WoutF + WOUT_ELEMS);

    prepack_kernel<<<(WP_ELEMS + WOUT_ELEMS + 255) / 256, 256, 0, stream>>>(
        W_ih, b_ih, W_hh, b_hh, W_out, Wp, WoutF, b_sum);

    vlstm_kernel<<<GRID, BLOCK, 0, stream>>>(
        nodes, mask, h0, c0, W_embed, b_embed, b_out, Wp, WoutF, b_sum, out);
}